// Round 1
// baseline (386.632 us; speedup 1.0000x reference)
//
#include <hip/hip_runtime.h>
#include <hip/hip_bf16.h>

#define NPOS 1568   // 8*14*14
#define NPAD 1600   // 25 * 64
#define DHEAD 128
#define DIM 256
#define NHEADS 4
#define SCALE 0.08838834764831845f  // 128^-0.5

typedef __bf16 bf16x8 __attribute__((ext_vector_type(8)));
typedef float f32x4 __attribute__((ext_vector_type(4)));
typedef unsigned short u16;
typedef u16 u16x8 __attribute__((ext_vector_type(8)));

__device__ __forceinline__ u16 f2bf(float x) {
  union { float f; unsigned int u; } v; v.f = x;
  return (u16)((v.u + 0x7FFFu + ((v.u >> 16) & 1u)) >> 16);
}

// ---------------- emb: [1568][128] f32 = pos_f + pos_h + pos_w ----------------
__global__ __launch_bounds__(256) void emb_kernel(
    const float* __restrict__ pf, const float* __restrict__ ph,
    const float* __restrict__ pw, float* __restrict__ emb) {
  int idx = blockIdx.x * 256 + threadIdx.x;     // 784 blocks * 256 = 1568*128 exactly
  int pos = idx >> 7, d = idx & 127;
  int jf = pos / 196; int r = pos - jf * 196; int jh = r / 14; int jw = r - jh * 14;
  emb[idx] = pf[jf * 128 + d] + ph[jh * 128 + d] + pw[jw * 128 + d];
}

// swizzled bf16x8 fragment read from a row-major [*][64] bf16 LDS tile (128B rows)
__device__ __forceinline__ bf16x8 lds_frag64(const u16* base, int row, int ks, int l15, int g) {
  int r = row + l15;
  int off = r * 128 + ((ks * 64 + g * 16) ^ ((r & 7) << 4));
  return *(const bf16x8*)((const char*)base + off);
}

// ---------------- projection: qkv = W_qkv @ fmap_b ----------------
// grid (25 pos-tiles, 24 o-tiles, 8 b), 256 threads. 64x64 output tile, K=256 in 4x64 steps.
union PSMem {
  struct { u16 wt[64 * 64]; u16 xt[64 * 64]; } s;   // 8KB + 8KB, both XOR-swizzled
  float o_lds[64 * 68];                              // 17408B epilogue transpose buffer
};

__global__ __launch_bounds__(256) void proj_kernel(
    const float* __restrict__ fmap, const float* __restrict__ W,
    const float* __restrict__ emb, u16* __restrict__ qws, u16* __restrict__ kws,
    u16* __restrict__ vws) {
  __shared__ PSMem sm;
  const int tid = threadIdx.x;
  const int lane = tid & 63, w = tid >> 6, l15 = lane & 15, g = lane >> 4;
  const int pos0 = blockIdx.x * 64, o0 = blockIdx.y * 64, b = blockIdx.z;

  f32x4 acc[4];
#pragma unroll
  for (int t = 0; t < 4; ++t) acc[t] = (f32x4){0.f, 0.f, 0.f, 0.f};

  for (int c0 = 0; c0 < DIM; c0 += 64) {
    // stage W tile [64 o][64 c] bf16, swizzled
    {
      int r = tid >> 2, c16 = (tid & 3) * 16;
      const float* src = W + (o0 + r) * DIM + c0 + c16;
      float4 f0 = *(const float4*)(src + 0);
      float4 f1 = *(const float4*)(src + 4);
      float4 f2 = *(const float4*)(src + 8);
      float4 f3 = *(const float4*)(src + 12);
      u16x8 a, bvv;
      a[0]=f2bf(f0.x); a[1]=f2bf(f0.y); a[2]=f2bf(f0.z); a[3]=f2bf(f0.w);
      a[4]=f2bf(f1.x); a[5]=f2bf(f1.y); a[6]=f2bf(f1.z); a[7]=f2bf(f1.w);
      bvv[0]=f2bf(f2.x); bvv[1]=f2bf(f2.y); bvv[2]=f2bf(f2.z); bvv[3]=f2bf(f2.w);
      bvv[4]=f2bf(f3.x); bvv[5]=f2bf(f3.y); bvv[6]=f2bf(f3.z); bvv[7]=f2bf(f3.w);
      int byte0 = r * 128 + ((c16 * 2) ^ ((r & 7) << 4));
      int byte1 = r * 128 + ((c16 * 2 + 16) ^ ((r & 7) << 4));
      *(u16x8*)((char*)sm.s.wt + byte0) = a;
      *(u16x8*)((char*)sm.s.wt + byte1) = bvv;
    }
    // stage X tile transposed -> xt[64 pos][64 c] bf16, swizzled
#pragma unroll
    for (int it = 0; it < 2; ++it) {
      int cl = (tid >> 3) + it * 32;
      int p8 = (tid & 7) * 8;
      int gp = pos0 + p8;
      if (gp > NPOS - 8) gp = NPOS - 8;   // clamp (pad cols are zeroed at store)
      const float* src = fmap + ((size_t)(b * DIM + c0 + cl)) * NPOS + gp;
      float4 f0 = *(const float4*)(src + 0);
      float4 f1 = *(const float4*)(src + 4);
      float vals[8] = {f0.x, f0.y, f0.z, f0.w, f1.x, f1.y, f1.z, f1.w};
#pragma unroll
      for (int i = 0; i < 8; ++i) {
        int pl = p8 + i;
        int byte = pl * 128 + ((cl * 2) ^ ((pl & 7) << 4));
        *(u16*)((char*)sm.s.xt + byte) = f2bf(vals[i]);
      }
    }
    __syncthreads();
#pragma unroll
    for (int ks = 0; ks < 2; ++ks) {
      bf16x8 aw = lds_frag64(sm.s.wt, w * 16, ks, l15, g);
#pragma unroll
      for (int t = 0; t < 4; ++t) {
        bf16x8 bx = lds_frag64(sm.s.xt, t * 16, ks, l15, g);
        acc[t] = __builtin_amdgcn_mfma_f32_16x16x32_bf16(aw, bx, acc[t], 0, 0, 0);
      }
    }
    __syncthreads();
  }

  const int sec = o0 >> 9;            // 0=q, 1=k, 2=v
  const int head = (o0 >> 7) & 3;
  const int dbase = o0 & 127;         // 0 or 64
  const int bh = b * NHEADS + head;

  // D layout: col(pos_local)=lane&15, row(o_local within 16)=4*(lane>>4)+reg
  if (sec < 2) {   // q,k: transpose to o_lds[pos][o] so global writes are [pos][d]-contiguous
#pragma unroll
    for (int t = 0; t < 4; ++t)
#pragma unroll
      for (int r = 0; r < 4; ++r)
        sm.o_lds[(t * 16 + l15) * 68 + (w * 16 + 4 * g + r)] = acc[t][r];
  } else {         // v: keep [o][pos] so global writes are [d][pos]-contiguous
#pragma unroll
    for (int t = 0; t < 4; ++t)
#pragma unroll
      for (int r = 0; r < 4; ++r)
        sm.o_lds[(w * 16 + 4 * g + r) * 68 + (t * 16 + l15)] = acc[t][r];
  }
  __syncthreads();

  if (sec == 0) {            // q: scale, layout [bh][pos][d]
#pragma unroll
    for (int it = 0; it < 2; ++it) {
      int cid = tid + it * 256;
      int p = cid >> 3, c8 = (cid & 7) * 8;
      int gpos = pos0 + p;
      u16x8 o;
      if (gpos < NPOS) {
#pragma unroll
        for (int i = 0; i < 8; ++i) o[i] = f2bf(sm.o_lds[p * 68 + c8 + i] * SCALE);
      } else {
#pragma unroll
        for (int i = 0; i < 8; ++i) o[i] = 0;
      }
      *(u16x8*)(qws + ((size_t)bh * NPAD + gpos) * DHEAD + dbase + c8) = o;
    }
  } else if (sec == 1) {     // k: + emb, layout [bh][pos][d]
#pragma unroll
    for (int it = 0; it < 2; ++it) {
      int cid = tid + it * 256;
      int p = cid >> 3, c8 = (cid & 7) * 8;
      int gpos = pos0 + p;
      u16x8 o;
      if (gpos < NPOS) {
        const float* eb = emb + (size_t)gpos * DHEAD + dbase + c8;
#pragma unroll
        for (int i = 0; i < 8; ++i) o[i] = f2bf(sm.o_lds[p * 68 + c8 + i] + eb[i]);
      } else {
#pragma unroll
        for (int i = 0; i < 8; ++i) o[i] = 0;
      }
      *(u16x8*)(kws + ((size_t)bh * NPAD + gpos) * DHEAD + dbase + c8) = o;
    }
  } else {                   // v: transposed layout [bh][d][pos]
#pragma unroll
    for (int it = 0; it < 2; ++it) {
      int cid = tid + it * 256;
      int r = cid >> 3, p8 = (cid & 7) * 8;
      u16x8 o;
      if (pos0 + p8 < NPOS) {
#pragma unroll
        for (int i = 0; i < 8; ++i) o[i] = f2bf(sm.o_lds[r * 68 + p8 + i]);
      } else {
#pragma unroll
        for (int i = 0; i < 8; ++i) o[i] = 0;
      }
      *(u16x8*)(vws + ((size_t)bh * DHEAD + dbase + r) * NPAD + pos0 + p8) = o;
    }
  }
}

// ---------------- attention: flash-style over 25 KV tiles of 64 ----------------
// grid (25 q-tiles, 32 bh), 256 threads = 4 waves x 16 q-rows.
union ASMem {
  struct { u16 kt[64 * 128]; u16 vt[128 * 64]; u16 pt[4 * 16 * 64]; } s;  // 40960B
  float o_lds[64 * 132];                                                   // 33792B
};

__global__ __launch_bounds__(256) void attn_kernel(
    const u16* __restrict__ qws, const u16* __restrict__ kws,
    const u16* __restrict__ vws, float* __restrict__ out) {
  __shared__ ASMem sm;
  const int tid = threadIdx.x;
  const int lane = tid & 63, w = tid >> 6, l15 = lane & 15, g = lane >> 4;
  const int bh = blockIdx.y, b = bh >> 2, h = bh & 3;
  const int q0 = blockIdx.x * 64;

  // Q fragments: rows q0+16w+l15, k-slices of 32 along d (pad rows are zero)
  bf16x8 aq[4];
  {
    const u16* qp = qws + ((size_t)bh * NPAD + q0 + w * 16 + l15) * DHEAD + g * 8;
#pragma unroll
    for (int s = 0; s < 4; ++s) aq[s] = *(const bf16x8*)(qp + s * 32);
  }

  float m[4], l[4];
  f32x4 oacc[8];
#pragma unroll
  for (int r = 0; r < 4; ++r) { m[r] = -1e30f; l[r] = 0.f; }
#pragma unroll
  for (int dt = 0; dt < 8; ++dt) oacc[dt] = (f32x4){0.f, 0.f, 0.f, 0.f};

  for (int jt = 0; jt < 25; ++jt) {
    const int j0 = jt * 64;
    // stage K tile [64 j][128 d] swizzled
#pragma unroll
    for (int it = 0; it < 4; ++it) {
      int cid = tid + it * 256;
      int row = cid >> 4, ch = cid & 15;
      uint4 v = *(const uint4*)(kws + ((size_t)bh * NPAD + j0 + row) * DHEAD + ch * 8);
      int byte = row * 256 + ((ch * 16) ^ ((row & 7) << 4));
      *(uint4*)((char*)sm.s.kt + byte) = v;
    }
    // stage V^T tile [128 d][64 j] swizzled
#pragma unroll
    for (int it = 0; it < 4; ++it) {
      int cid = tid + it * 256;
      int row = cid >> 3, ch = cid & 7;
      uint4 v = *(const uint4*)(vws + ((size_t)bh * DHEAD + row) * NPAD + j0 + ch * 8);
      int byte = row * 128 + ((ch * 16) ^ ((row & 7) << 4));
      *(uint4*)((char*)sm.s.vt + byte) = v;
    }
    __syncthreads();

    // S = Q K'^T : rows=q (4g+reg), cols=j (l15), 4 j-subtiles
    f32x4 sc[4];
#pragma unroll
    for (int t = 0; t < 4; ++t) {
      sc[t] = (f32x4){0.f, 0.f, 0.f, 0.f};
#pragma unroll
      for (int s = 0; s < 4; ++s) {
        int r = t * 16 + l15;
        int byte = r * 256 + ((s * 64 + g * 16) ^ ((r & 7) << 4));
        bf16x8 kb = *(const bf16x8*)((const char*)sm.s.kt + byte);
        sc[t] = __builtin_amdgcn_mfma_f32_16x16x32_bf16(aq[s], kb, sc[t], 0, 0, 0);
      }
    }
    // mask tail keys, online softmax
    float pm[4] = {-1e30f, -1e30f, -1e30f, -1e30f};
#pragma unroll
    for (int t = 0; t < 4; ++t) {
      if (j0 + t * 16 + l15 >= NPOS) sc[t] = (f32x4){-1e30f, -1e30f, -1e30f, -1e30f};
#pragma unroll
      for (int r = 0; r < 4; ++r) pm[r] = fmaxf(pm[r], sc[t][r]);
    }
#pragma unroll
    for (int mk = 1; mk <= 8; mk <<= 1)
#pragma unroll
      for (int r = 0; r < 4; ++r) pm[r] = fmaxf(pm[r], __shfl_xor(pm[r], mk));
    float alpha[4], ps[4];
#pragma unroll
    for (int r = 0; r < 4; ++r) {
      float mn = fmaxf(m[r], pm[r]);
      alpha[r] = __expf(m[r] - mn);
      m[r] = mn;
      ps[r] = 0.f;
    }
    float p[4][4];
#pragma unroll
    for (int t = 0; t < 4; ++t)
#pragma unroll
      for (int r = 0; r < 4; ++r) {
        p[t][r] = __expf(sc[t][r] - m[r]);
        ps[r] += p[t][r];
      }
#pragma unroll
    for (int mk = 1; mk <= 8; mk <<= 1)
#pragma unroll
      for (int r = 0; r < 4; ++r) ps[r] += __shfl_xor(ps[r], mk);
#pragma unroll
    for (int r = 0; r < 4; ++r) l[r] = l[r] * alpha[r] + ps[r];
#pragma unroll
    for (int dt = 0; dt < 8; ++dt)
#pragma unroll
      for (int r = 0; r < 4; ++r) oacc[dt][r] *= alpha[r];

    // P (D-layout) -> per-wave swizzled LDS tile [16 i][64 j] -> A-layout frags
    u16* pwav = sm.s.pt + w * 1024;
#pragma unroll
    for (int t = 0; t < 4; ++t)
#pragma unroll
      for (int r = 0; r < 4; ++r) {
        int il = 4 * g + r, jc = t * 16 + l15;
        int byte = il * 128 + ((jc * 2) ^ ((il & 7) << 4));
        *(u16*)((char*)pwav + byte) = f2bf(p[t][r]);
      }
    bf16x8 pa[2];
#pragma unroll
    for (int ks = 0; ks < 2; ++ks) {
      int byte = l15 * 128 + ((ks * 64 + g * 16) ^ ((l15 & 7) << 4));
      pa[ks] = *(const bf16x8*)((const char*)pwav + byte);
    }
    // O += P V : rows=q, cols=d (8 d-subtiles), contraction over 64 j (2 slices)
#pragma unroll
    for (int dt = 0; dt < 8; ++dt)
#pragma unroll
      for (int ks = 0; ks < 2; ++ks) {
        int dr = dt * 16 + l15;
        int byte = dr * 128 + ((ks * 64 + g * 16) ^ ((dr & 7) << 4));
        bf16x8 vb = *(const bf16x8*)((const char*)sm.s.vt + byte);
        oacc[dt] = __builtin_amdgcn_mfma_f32_16x16x32_bf16(pa[ks], vb, oacc[dt], 0, 0, 0);
      }
    __syncthreads();
  }

  // epilogue: normalize, LDS-transpose, coalesced [channel][pos] f32 stores
#pragma unroll
  for (int r = 0; r < 4; ++r) l[r] = 1.0f / l[r];
#pragma unroll
  for (int dt = 0; dt < 8; ++dt)
#pragma unroll
    for (int r = 0; r < 4; ++r) {
      int ql = w * 16 + 4 * g + r;
      sm.o_lds[ql * 132 + dt * 16 + l15] = oacc[dt][r] * l[r];
    }
  __syncthreads();
  {
    int d = tid >> 1, p0 = (tid & 1) * 32;
    float* dst = out + ((size_t)(b * 512 + h * 128 + d)) * NPOS + q0 + p0;
#pragma unroll
    for (int ci = 0; ci < 8; ++ci) {
      int p = p0 + ci * 4;
      if (q0 + p < NPOS) {
        float4 v;
        v.x = sm.o_lds[(p + 0) * 132 + d];
        v.y = sm.o_lds[(p + 1) * 132 + d];
        v.z = sm.o_lds[(p + 2) * 132 + d];
        v.w = sm.o_lds[(p + 3) * 132 + d];
        *(float4*)(dst + ci * 4) = v;
      }
    }
  }
}

extern "C" void kernel_launch(void* const* d_in, const int* in_sizes, int n_in,
                              void* d_out, int out_size, void* d_ws, size_t ws_size,
                              hipStream_t stream) {
  const float* fmap = (const float*)d_in[0];
  const float* W    = (const float*)d_in[1];
  const float* pf   = (const float*)d_in[2];
  const float* ph   = (const float*)d_in[3];
  const float* pw   = (const float*)d_in[4];
  float* out = (float*)d_out;

  char* ws = (char*)d_ws;
  const size_t SZ = (size_t)32 * NPAD * DHEAD * 2;  // 13107200 B per tensor
  u16* qws = (u16*)ws;
  u16* kws = (u16*)(ws + SZ);
  u16* vws = (u16*)(ws + 2 * SZ);
  float* emb = (float*)(ws + 3 * SZ);               // [1568][128] f32

  emb_kernel<<<dim3(784), dim3(256), 0, stream>>>(pf, ph, pw, emb);
  proj_kernel<<<dim3(25, 24, 8), dim3(256), 0, stream>>>(fmap, W, emb, qws, kws, vws);
  attn_kernel<<<dim3(25, 32), dim3(256), 0, stream>>>(qws, kws, vws, out);
}

// Round 3
// 137.068 us; speedup vs baseline: 2.8207x; 2.8207x over previous
//
#include <hip/hip_runtime.h>
#include <hip/hip_bf16.h>
#include <cstdint>

#define NPOS 1568   // 8*14*14
#define NQPAD 1664  // 13 * 128 (q rows, padded)
#define NKVT 25     // kv tiles of 64 (25*64 = 1600)
#define DHEAD 128
#define DIM 256
#define NHEADS 4
// scale * log2(e): softmax computed in log2 domain (raw v_exp_f32)
#define SCALE_Q (0.08838834764831845f * 1.4426950408889634f)

typedef __bf16 bf16x8 __attribute__((ext_vector_type(8)));
typedef float f32x4 __attribute__((ext_vector_type(4)));
typedef float f32x16 __attribute__((ext_vector_type(16)));
typedef unsigned short u16;
typedef u16 u16x8 __attribute__((ext_vector_type(8)));

__device__ __forceinline__ u16 f2bf(float x) {
  union { float f; unsigned int u; } v; v.f = x;
  return (u16)((v.u + 0x7FFFu + ((v.u >> 16) & 1u)) >> 16);
}

__device__ __forceinline__ unsigned cvtpk(float a, float b) {
  unsigned r;
  asm("v_cvt_pk_bf16_f32 %0, %1, %2" : "=v"(r) : "v"(a), "v"(b));
  return r;
}

// async global->LDS, 16B per lane; dst is wave-uniform base (HW adds lane*16)
__device__ __forceinline__ void gload_lds16(const void* g, void* s) {
  __builtin_amdgcn_global_load_lds(
      (const __attribute__((address_space(1))) unsigned*)g,
      (__attribute__((address_space(3))) unsigned*)s, 16, 0, 0);
}

__device__ __forceinline__ f32x16 zero16() {
  f32x16 v;
#pragma unroll
  for (int i = 0; i < 16; ++i) v[i] = 0.f;
  return v;
}

// ---------------- emb: [1568][128] f32 = pos_f + pos_h + pos_w ----------------
__global__ __launch_bounds__(256) void emb_kernel(
    const float* __restrict__ pf, const float* __restrict__ ph,
    const float* __restrict__ pw, float* __restrict__ emb) {
  int idx = blockIdx.x * 256 + threadIdx.x;
  int pos = idx >> 7, d = idx & 127;
  int jf = pos / 196; int r = pos - jf * 196; int jh = r / 14; int jw = r - jh * 14;
  emb[idx] = pf[jf * 128 + d] + ph[jh * 128 + d] + pw[jw * 128 + d];
}

// swizzled bf16x8 fragment read from a row-major [*][64] bf16 LDS tile (128B rows)
__device__ __forceinline__ bf16x8 lds_frag64(const u16* base, int row, int ks, int l15, int g) {
  int r = row + l15;
  int off = r * 128 + ((ks * 64 + g * 16) ^ ((r & 7) << 4));
  return *(const bf16x8*)((const char*)base + off);
}

// ---------------- projection: qkv = W_qkv @ fmap_b ----------------
// grid (26 pos-tiles, 24 o-tiles, 8 b), 256 threads. 64x64 output tile, K=256.
union PSMem {
  struct { u16 wt[64 * 64]; u16 xt[64 * 64]; } s;
  float o_lds[64 * 68];
};

__global__ __launch_bounds__(256) void proj_kernel(
    const float* __restrict__ fmap, const float* __restrict__ W,
    const float* __restrict__ emb, u16* __restrict__ qws, char* __restrict__ tiles) {
  __shared__ PSMem sm;
  const int tid = threadIdx.x;
  const int lane = tid & 63, w = tid >> 6, l15 = lane & 15, g = lane >> 4;
  const int pos0 = blockIdx.x * 64, o0 = blockIdx.y * 64, b = blockIdx.z;

  f32x4 acc[4];
#pragma unroll
  for (int t = 0; t < 4; ++t) acc[t] = (f32x4){0.f, 0.f, 0.f, 0.f};

  for (int c0 = 0; c0 < DIM; c0 += 64) {
    {
      int r = tid >> 2, c16 = (tid & 3) * 16;
      const float* src = W + (o0 + r) * DIM + c0 + c16;
      float4 f0 = *(const float4*)(src + 0);
      float4 f1 = *(const float4*)(src + 4);
      float4 f2 = *(const float4*)(src + 8);
      float4 f3 = *(const float4*)(src + 12);
      u16x8 a, bvv;
      a[0]=f2bf(f0.x); a[1]=f2bf(f0.y); a[2]=f2bf(f0.z); a[3]=f2bf(f0.w);
      a[4]=f2bf(f1.x); a[5]=f2bf(f1.y); a[6]=f2bf(f1.z); a[7]=f2bf(f1.w);
      bvv[0]=f2bf(f2.x); bvv[1]=f2bf(f2.y); bvv[2]=f2bf(f2.z); bvv[3]=f2bf(f2.w);
      bvv[4]=f2bf(f3.x); bvv[5]=f2bf(f3.y); bvv[6]=f2bf(f3.z); bvv[7]=f2bf(f3.w);
      int byte0 = r * 128 + ((c16 * 2) ^ ((r & 7) << 4));
      int byte1 = r * 128 + ((c16 * 2 + 16) ^ ((r & 7) << 4));
      *(u16x8*)((char*)sm.s.wt + byte0) = a;
      *(u16x8*)((char*)sm.s.wt + byte1) = bvv;
    }
#pragma unroll
    for (int it = 0; it < 2; ++it) {
      int cl = (tid >> 3) + it * 32;
      int p8 = (tid & 7) * 8;
      int gp = pos0 + p8;
      if (gp > NPOS - 8) gp = NPOS - 8;
      const float* src = fmap + ((size_t)(b * DIM + c0 + cl)) * NPOS + gp;
      float4 f0 = *(const float4*)(src + 0);
      float4 f1 = *(const float4*)(src + 4);
      float vals[8] = {f0.x, f0.y, f0.z, f0.w, f1.x, f1.y, f1.z, f1.w};
#pragma unroll
      for (int i = 0; i < 8; ++i) {
        int pl = p8 + i;
        int byte = pl * 128 + ((cl * 2) ^ ((pl & 7) << 4));
        *(u16*)((char*)sm.s.xt + byte) = f2bf(vals[i]);
      }
    }
    __syncthreads();
#pragma unroll
    for (int ks = 0; ks < 2; ++ks) {
      bf16x8 aw = lds_frag64(sm.s.wt, w * 16, ks, l15, g);
#pragma unroll
      for (int t = 0; t < 4; ++t) {
        bf16x8 bx = lds_frag64(sm.s.xt, t * 16, ks, l15, g);
        acc[t] = __builtin_amdgcn_mfma_f32_16x16x32_bf16(aw, bx, acc[t], 0, 0, 0);
      }
    }
    __syncthreads();
  }

  const int sec = o0 >> 9;            // 0=q, 1=k, 2=v
  const int head = (o0 >> 7) & 3;
  const int dbase = o0 & 127;
  const int bh = b * NHEADS + head;

  if (sec < 2) {
#pragma unroll
    for (int t = 0; t < 4; ++t)
#pragma unroll
      for (int r = 0; r < 4; ++r)
        sm.o_lds[(t * 16 + l15) * 68 + (w * 16 + 4 * g + r)] = acc[t][r];
  } else {
#pragma unroll
    for (int t = 0; t < 4; ++t)
#pragma unroll
      for (int r = 0; r < 4; ++r)
        sm.o_lds[(w * 16 + 4 * g + r) * 68 + (t * 16 + l15)] = acc[t][r];
  }
  __syncthreads();

  if (sec == 0) {            // q: scale (incl log2e), linear [bh][pos][d], pad->0
#pragma unroll
    for (int it = 0; it < 2; ++it) {
      int cid = tid + it * 256;
      int p = cid >> 3, c8 = (cid & 7) * 8;
      int gpos = pos0 + p;
      u16x8 o;
      if (gpos < NPOS) {
#pragma unroll
        for (int i = 0; i < 8; ++i) o[i] = f2bf(sm.o_lds[p * 68 + c8 + i] * SCALE_Q);
      } else {
#pragma unroll
        for (int i = 0; i < 8; ++i) o[i] = 0;
      }
      *(u16x8*)(qws + ((size_t)bh * NQPAD + gpos) * DHEAD + dbase + c8) = o;
    }
  } else if (sec == 1) {     // k: + emb -> swizzled K-tile image [64][256B]
    if (pos0 < NKVT * 64) {
#pragma unroll
      for (int it = 0; it < 2; ++it) {
        int cid = tid + it * 256;
        int p = cid >> 3, c8 = (cid & 7) * 8;
        int gpos = pos0 + p;
        u16x8 o;
        if (gpos < NPOS) {
          const float* eb = emb + (size_t)gpos * DHEAD + dbase + c8;
#pragma unroll
          for (int i = 0; i < 8; ++i) o[i] = f2bf(sm.o_lds[p * 68 + c8 + i] + eb[i]);
        } else {
#pragma unroll
          for (int i = 0; i < 8; ++i) o[i] = 0;
        }
        int jt = gpos >> 6, jl = gpos & 63;
        char* dst = tiles + ((size_t)(bh * NKVT + jt)) * 32768 + jl * 256 +
                    (((dbase + c8) * 2) ^ ((jl & 7) << 4));
        *(u16x8*)dst = o;
      }
    }
  } else {                   // v: V^T tile image [128 d][64 j] at +16KB
    if (pos0 < NKVT * 64) {
      int jt = pos0 >> 6;
#pragma unroll
      for (int it = 0; it < 2; ++it) {
        int cid = tid + it * 256;
        int r = cid >> 3, p8 = (cid & 7) * 8;
        int d = dbase + r;
        u16x8 o;
        if (pos0 + p8 < NPOS) {
#pragma unroll
          for (int i = 0; i < 8; ++i) o[i] = f2bf(sm.o_lds[r * 68 + p8 + i]);
        } else {
#pragma unroll
          for (int i = 0; i < 8; ++i) o[i] = 0;
        }
        char* dst = tiles + ((size_t)(bh * NKVT + jt)) * 32768 + 16384 + d * 128 +
                    ((p8 * 2) ^ ((d & 7) << 4));
        *(u16x8*)dst = o;
      }
    }
  }
}

// ---------------- attention: 4 waves x 32 q-rows, swapped 32x32 MFMA ----------------
// grid (13, 32). LDS: 2 x (16KB K-tile + 16KB V^T-tile) double buffer.
// K rows are read through rho(l31) = bits2<->3 swap, so the S^T D-layout lands
// directly in B-operand slot order for PV (no cross-lane P exchange needed).
__global__ __launch_bounds__(256) void attn_kernel(
    const u16* __restrict__ qws, const char* __restrict__ tiles,
    float* __restrict__ out) {
  __shared__ char smem[65536];
  const int tid = threadIdx.x;
  const int lane = tid & 63, w = tid >> 6;
  const int l31 = lane & 31, hi = lane >> 5;
  const int bh = blockIdx.y, b = bh >> 2, h = bh & 3;
  const int q0 = blockIdx.x * 128;
  // rho: swap bits 2 and 3 (involution)
  const int rho = (l31 & 0x13) | ((l31 & 4) << 1) | ((l31 & 8) >> 1);

  // Q B-frags: q = q0 + 32w + l31, d = kk*16 + 8*hi + i
  bf16x8 qf[8];
  {
    const u16* qp = qws + ((size_t)bh * NQPAD + q0 + w * 32 + l31) * DHEAD + 8 * hi;
#pragma unroll
    for (int kk = 0; kk < 8; ++kk) qf[kk] = *(const bf16x8*)(qp + kk * 16);
  }

  f32x16 oacc[4];
#pragma unroll
  for (int dt = 0; dt < 4; ++dt) oacc[dt] = zero16();
  float m = -1e30f, l = 0.f;

  const size_t tbase = (size_t)bh * NKVT * 32768;

  {  // prologue: stage tile 0 -> buf0
    const char* src = tiles + tbase + w * 8192 + lane * 16;
    char* dst = smem + w * 8192;
#pragma unroll
    for (int i = 0; i < 8; ++i) gload_lds16(src + i * 1024, dst + i * 1024);
  }
  __syncthreads();

  int cur = 0;
  for (int jt = 0; jt < NKVT; ++jt) {
    if (jt + 1 < NKVT) {  // prefetch next tile into other buffer (latency hidden)
      const char* src = tiles + tbase + (size_t)(jt + 1) * 32768 + w * 8192 + lane * 16;
      char* dst = smem + (cur ^ 1) * 32768 + w * 8192;
#pragma unroll
      for (int i = 0; i < 8; ++i) gload_lds16(src + i * 1024, dst + i * 1024);
    }
    const char* kt = smem + cur * 32768;
    const char* vt = kt + 16384;
    const bool full = (jt < NKVT - 1);  // last tile: only first 32 of 64 keys valid

    // S^T = mfma(K[rho-rows], Q): sc[r] = S[q=l31][j0 + 16*(r>>3) + 8*hi + (r&7)]
    f32x16 sc0 = zero16(), sc1 = zero16();
    {
      int row = rho, swz = (row & 7) << 4;
#pragma unroll
      for (int kk = 0; kk < 8; ++kk) {
        bf16x8 ka = *(const bf16x8*)(kt + row * 256 + ((kk * 32 + 16 * hi) ^ swz));
        sc0 = __builtin_amdgcn_mfma_f32_32x32x16_bf16(ka, qf[kk], sc0, 0, 0, 0);
      }
    }
    if (full) {
      int row = 32 + rho, swz = (row & 7) << 4;
#pragma unroll
      for (int kk = 0; kk < 8; ++kk) {
        bf16x8 ka = *(const bf16x8*)(kt + row * 256 + ((kk * 32 + 16 * hi) ^ swz));
        sc1 = __builtin_amdgcn_mfma_f32_32x32x16_bf16(ka, qf[kk], sc1, 0, 0, 0);
      }
    }

    // online softmax (log2 domain), lane-local q; partial l per hi-half
    float pm = -1e30f;
#pragma unroll
    for (int i = 0; i < 16; ++i) pm = fmaxf(pm, sc0[i]);
    if (full) {
#pragma unroll
      for (int i = 0; i < 16; ++i) pm = fmaxf(pm, sc1[i]);
    }
    pm = fmaxf(pm, __shfl_xor(pm, 32));
    if (!__all(pm <= m + 8.f)) {  // defer-max (THR=8 in log2 units)
      float mn = fmaxf(m, pm);
      float al = exp2f(m - mn);
      m = mn;
      l *= al;
#pragma unroll
      for (int dt = 0; dt < 4; ++dt)
#pragma unroll
        for (int i = 0; i < 16; ++i) oacc[dt][i] *= al;
    }
    float lac = 0.f;
#pragma unroll
    for (int i = 0; i < 16; ++i) { sc0[i] = exp2f(sc0[i] - m); lac += sc0[i]; }
    if (full) {
#pragma unroll
      for (int i = 0; i < 16; ++i) { sc1[i] = exp2f(sc1[i] - m); lac += sc1[i]; }
    }
    l += lac;

    // P -> B-frags: pure in-lane packing (slot i of slice s is sc[8s+i])
    {
      union { unsigned u[4]; bf16x8 v; } pb0, pb1;
      pb0.u[0] = cvtpk(sc0[0], sc0[1]);  pb0.u[1] = cvtpk(sc0[2], sc0[3]);
      pb0.u[2] = cvtpk(sc0[4], sc0[5]);  pb0.u[3] = cvtpk(sc0[6], sc0[7]);
      pb1.u[0] = cvtpk(sc0[8], sc0[9]);  pb1.u[1] = cvtpk(sc0[10], sc0[11]);
      pb1.u[2] = cvtpk(sc0[12], sc0[13]); pb1.u[3] = cvtpk(sc0[14], sc0[15]);
#pragma unroll
      for (int dt = 0; dt < 4; ++dt) {
        int row = dt * 32 + l31, swz = (row & 7) << 4;
        bf16x8 va0 = *(const bf16x8*)(vt + row * 128 + ((16 * hi) ^ swz));
        oacc[dt] = __builtin_amdgcn_mfma_f32_32x32x16_bf16(va0, pb0.v, oacc[dt], 0, 0, 0);
        bf16x8 va1 = *(const bf16x8*)(vt + row * 128 + ((32 + 16 * hi) ^ swz));
        oacc[dt] = __builtin_amdgcn_mfma_f32_32x32x16_bf16(va1, pb1.v, oacc[dt], 0, 0, 0);
      }
    }
    if (full) {
      union { unsigned u[4]; bf16x8 v; } pb0, pb1;
      pb0.u[0] = cvtpk(sc1[0], sc1[1]);  pb0.u[1] = cvtpk(sc1[2], sc1[3]);
      pb0.u[2] = cvtpk(sc1[4], sc1[5]);  pb0.u[3] = cvtpk(sc1[6], sc1[7]);
      pb1.u[0] = cvtpk(sc1[8], sc1[9]);  pb1.u[1] = cvtpk(sc1[10], sc1[11]);
      pb1.u[2] = cvtpk(sc1[12], sc1[13]); pb1.u[3] = cvtpk(sc1[14], sc1[15]);
#pragma unroll
      for (int dt = 0; dt < 4; ++dt) {
        int row = dt * 32 + l31, swz = (row & 7) << 4;
        bf16x8 va0 = *(const bf16x8*)(vt + row * 128 + ((64 + 16 * hi) ^ swz));
        oacc[dt] = __builtin_amdgcn_mfma_f32_32x32x16_bf16(va0, pb0.v, oacc[dt], 0, 0, 0);
        bf16x8 va1 = *(const bf16x8*)(vt + row * 128 + ((96 + 16 * hi) ^ swz));
        oacc[dt] = __builtin_amdgcn_mfma_f32_32x32x16_bf16(va1, pb1.v, oacc[dt], 0, 0, 0);
      }
    }
    __syncthreads();  // drains prefetch vmcnt too -> next buf ready
    cur ^= 1;
  }

  // epilogue: combine l across hi-halves, normalize, direct [chan][pos] stores
  float lt = l + __shfl_xor(l, 32);
  float linv = 1.f / lt;
  const int q = q0 + w * 32 + l31;
  if (q < NPOS) {
    float* ob = out + (size_t)(b * 512 + h * 128) * NPOS + q;
#pragma unroll
    for (int dt = 0; dt < 4; ++dt)
#pragma unroll
      for (int r = 0; r < 16; ++r) {
        int d = dt * 32 + (r & 3) + 8 * (r >> 2) + 4 * hi;
        ob[(size_t)d * NPOS] = oacc[dt][r] * linv;
      }
  }
}

extern "C" void kernel_launch(void* const* d_in, const int* in_sizes, int n_in,
                              void* d_out, int out_size, void* d_ws, size_t ws_size,
                              hipStream_t stream) {
  const float* fmap = (const float*)d_in[0];
  const float* W    = (const float*)d_in[1];
  const float* pf   = (const float*)d_in[2];
  const float* ph   = (const float*)d_in[3];
  const float* pw   = (const float*)d_in[4];
  float* out = (float*)d_out;

  char* ws = (char*)d_ws;
  const size_t QSZ = (size_t)32 * NQPAD * DHEAD * 2;       // 13,631,488
  const size_t TSZ = (size_t)32 * NKVT * 32768;            // 26,214,400
  u16* qws = (u16*)ws;
  char* tiles = ws + QSZ;
  float* emb = (float*)(ws + QSZ + TSZ);

  emb_kernel<<<dim3(784), dim3(256), 0, stream>>>(pf, ph, pw, emb);
  proj_kernel<<<dim3(26, 24, 8), dim3(256), 0, stream>>>(fmap, W, emb, qws, tiles);
  attn_kernel<<<dim3(13, 32), dim3(256), 0, stream>>>(qws, tiles, out);
}